// Round 1
// baseline (5636.180 us; speedup 1.0000x reference)
//
#include <hip/hip_runtime.h>
#include <cstdint>
#include <cstddef>

#define BATCH   8
#define NPTS    8192
#define NPOINT  2048
#define NSAMPLE 64
#define K0      67      // 3 + 64 input channels
#define C2      128

// Exact-order squared distance, matching XLA/numpy: ((dx*dx + dy*dy) + dz*dz),
// separate mul/add (no FMA contraction), round-to-nearest f32.
__device__ __forceinline__ float d2e(float ax, float ay, float az,
                                     float bx, float by, float bz) {
#pragma clang fp contract(off)
  float dx = ax - bx;
  float dy = ay - by;
  float dz = az - bz;
  float t0 = dx * dx;
  float t1 = dy * dy;
  float t2 = dz * dz;
  return (t0 + t1) + t2;
}

// ---------------- FPS: one block per batch, serial 2047-step argmax ----------
__global__ __launch_bounds__(512) void fps_kernel(const float* __restrict__ xyz,
                                                  float* __restrict__ out_xyz,
                                                  float* __restrict__ out_inds) {
  const int b = blockIdx.x;
  const int tid = threadIdx.x;
  const int lane = tid & 63, wid = tid >> 6;
  __shared__ float sx[NPTS], sy[NPTS], sz[NPTS];
  __shared__ float red_v[8];
  __shared__ int   red_i[8];

  const float* xb = xyz + (size_t)b * NPTS * 3;
  float px_[16], py_[16], pz_[16], dd[16];
  const float x0 = xb[0], y0 = xb[1], z0 = xb[2];

#pragma unroll
  for (int j = 0; j < 16; j++) {
    int i = tid + 512 * j;
    float xx = xb[i * 3 + 0], yy = xb[i * 3 + 1], zz = xb[i * 3 + 2];
    px_[j] = xx; py_[j] = yy; pz_[j] = zz;
    sx[i] = xx; sy[i] = yy; sz[i] = zz;
    dd[j] = d2e(xx, yy, zz, x0, y0, z0);
  }
  float bv = -1.f; int bi = 0;
#pragma unroll
  for (int j = 0; j < 16; j++) {
    if (dd[j] > bv) { bv = dd[j]; bi = tid + 512 * j; }  // strict > : first idx wins
  }
  if (tid == 0) {
    out_inds[b * NPOINT] = 0.f;
    out_xyz[(size_t)b * NPOINT * 3 + 0] = x0;
    out_xyz[(size_t)b * NPOINT * 3 + 1] = y0;
    out_xyz[(size_t)b * NPOINT * 3 + 2] = z0;
  }
  __syncthreads();

  for (int t = 1; t < NPOINT; ++t) {
    // wave-level argmax (value desc, index asc on ties — matches jnp.argmax)
    float v = bv; int idx = bi;
#pragma unroll
    for (int m = 1; m < 64; m <<= 1) {
      float ov = __shfl_xor(v, m, 64);
      int   oi = __shfl_xor(idx, m, 64);
      if (ov > v || (ov == v && oi < idx)) { v = ov; idx = oi; }
    }
    if (lane == 0) { red_v[wid] = v; red_i[wid] = idx; }
    __syncthreads();
    float fv = red_v[0]; int fi = red_i[0];
#pragma unroll
    for (int w = 1; w < 8; w++) {
      float rv = red_v[w]; int ri = red_i[w];
      if (rv > fv || (rv == fv && ri < fi)) { fv = rv; fi = ri; }
    }
    const int nxt = fi;
    const float qx = sx[nxt], qy = sy[nxt], qz = sz[nxt];
    if (tid == 0) {
      out_inds[b * NPOINT + t] = (float)nxt;
      out_xyz[((size_t)b * NPOINT + t) * 3 + 0] = qx;
      out_xyz[((size_t)b * NPOINT + t) * 3 + 1] = qy;
      out_xyz[((size_t)b * NPOINT + t) * 3 + 2] = qz;
    }
    __syncthreads();   // protect red_* before next iteration's writes

    bv = -1.f; bi = 0;
#pragma unroll
    for (int j = 0; j < 16; j++) {
      float d = d2e(px_[j], py_[j], pz_[j], qx, qy, qz);
      dd[j] = fminf(dd[j], d);
      if (dd[j] > bv) { bv = dd[j]; bi = tid + 512 * j; }
    }
  }
}

// ---------------- feature transpose: [b][c][n] -> [b][n][c] ------------------
__global__ __launch_bounds__(256) void transpose_kernel(const float* __restrict__ feat,
                                                        float* __restrict__ featT) {
  __shared__ float tile[64][65];
  const int bt = blockIdx.x;          // b*128 + ntile
  const int b = bt >> 7, nt = bt & 127;
  const int tid = threadIdx.x;
  const int r0 = tid >> 6, cc = tid & 63;
  const float* fb = feat + (size_t)b * 64 * NPTS + (size_t)nt * 64;
#pragma unroll
  for (int r = r0; r < 64; r += 4)
    tile[r][cc] = fb[(size_t)r * NPTS + cc];
  __syncthreads();
  float* ob = featT + ((size_t)b * NPTS + (size_t)nt * 64) * 64;
#pragma unroll
  for (int n = r0; n < 64; n += 4)
    ob[(size_t)n * 64 + cc] = tile[cc][n];
}

// ---------------- ball query: one wave per query point -----------------------
__global__ __launch_bounds__(256) void ballq_kernel(const float* __restrict__ xyz,
                                                    const float* __restrict__ new_xyz,
                                                    int* __restrict__ ball) {
  const int lane = threadIdx.x & 63;
  const int q = blockIdx.x * 4 + (threadIdx.x >> 6);
  const int b = q >> 11;
  const float RR = (float)(0.4 * 0.4);
  const float cx = new_xyz[(size_t)q * 3 + 0];
  const float cy = new_xyz[(size_t)q * 3 + 1];
  const float cz = new_xyz[(size_t)q * 3 + 2];
  const float* xb = xyz + (size_t)b * NPTS * 3;
  int cnt = 0, firsti = -1;
  for (int base = 0; base < NPTS; base += 64) {
    int i = base + lane;
    float xx = xb[i * 3 + 0], yy = xb[i * 3 + 1], zz = xb[i * 3 + 2];
    float d2 = d2e(xx, yy, zz, cx, cy, cz);
    bool m = d2 < RR;
    unsigned long long mask = __ballot(m);
    if (mask) {
      if (firsti < 0) firsti = base + (__ffsll((unsigned long long)mask) - 1);
      int pos = cnt + (int)__popcll(mask & ((1ull << lane) - 1ull));
      if (m && pos < NSAMPLE) ball[(size_t)q * NSAMPLE + pos] = i;
      cnt += (int)__popcll(mask);
      if (cnt >= NSAMPLE) break;
    }
  }
  // pad with first in-radius index (center itself is always in-radius -> cnt>=1)
  for (int s = cnt + lane; s < NSAMPLE; s += 64)
    ball[(size_t)q * NSAMPLE + s] = firsti;
}

// ---------------- grouped MLP (3 layers) + max-pool: one wave per point ------
__global__ __launch_bounds__(256) void mlp_kernel(
    const float* __restrict__ xyz, const float* __restrict__ featT,
    const int* __restrict__ ball, const float* __restrict__ new_xyz,
    const float* __restrict__ W0, const float* __restrict__ g0,
    const float* __restrict__ b0, const float* __restrict__ m0,
    const float* __restrict__ v0, const float* __restrict__ W1,
    const float* __restrict__ g1, const float* __restrict__ b1,
    const float* __restrict__ m1, const float* __restrict__ v1,
    const float* __restrict__ W2, const float* __restrict__ g2,
    const float* __restrict__ b2, const float* __restrict__ m2,
    const float* __restrict__ v2, float* __restrict__ out_feat) {
  __shared__ float bufA[4][K0 * 65];   // X (67 rows), later reused for Y1 (64 rows)
  __shared__ float bufB[4][64 * 65];   // Y0
  __shared__ float sc0[64], sh0[64], sc1[64], sh1[64], sc2[128], sh2[128];
  const int tid = threadIdx.x;
  const int lane = tid & 63, wid = tid >> 6;

  if (tid < 64) {
    float s = g0[tid] / sqrtf(v0[tid] + 1e-5f);
    sc0[tid] = s; sh0[tid] = b0[tid] - m0[tid] * s;
  } else if (tid < 128) {
    int t = tid - 64;
    float s = g1[t] / sqrtf(v1[t] + 1e-5f);
    sc1[t] = s; sh1[t] = b1[t] - m1[t] * s;
  } else {
    int t = tid - 128;
    float s = g2[t] / sqrtf(v2[t] + 1e-5f);
    sc2[t] = s; sh2[t] = b2[t] - m2[t] * s;
  }

  const int q = blockIdx.x * 4 + wid;
  const int b = q >> 11, p = q & 2047;
  float* XA = bufA[wid];
  float* XB = bufB[wid];

  const float cx = new_xyz[(size_t)q * 3 + 0];
  const float cy = new_xyz[(size_t)q * 3 + 1];
  const float cz = new_xyz[(size_t)q * 3 + 2];
  const int sidx = ball[(size_t)q * NSAMPLE + lane];
  const float* xb = xyz + (size_t)b * NPTS * 3;
  XA[0 * 65 + lane] = xb[(size_t)sidx * 3 + 0] - cx;
  XA[1 * 65 + lane] = xb[(size_t)sidx * 3 + 1] - cy;
  XA[2 * 65 + lane] = xb[(size_t)sidx * 3 + 2] - cz;
  const float* ftb = featT + (size_t)b * NPTS * 64;
  for (int s = 0; s < 64; ++s) {
    int ii = __shfl(sidx, s, 64);
    XA[(3 + lane) * 65 + s] = ftb[(size_t)ii * 64 + lane];   // coalesced 256B row
  }
  __syncthreads();   // also covers sc*/sh* visibility

  // ---- layer 0: 67 -> 64
  {
    float x[K0];
#pragma unroll
    for (int i = 0; i < K0; i++) x[i] = XA[i * 65 + lane];
#pragma unroll 2
    for (int o = 0; o < 64; o++) {
      const float* wr = W0 + o * K0;                       // wave-uniform row
      float a0 = 0.f, a1 = 0.f, a2 = 0.f, a3 = 0.f;
#pragma unroll
      for (int i = 0; i < 64; i += 4) {
        a0 = fmaf(wr[i + 0], x[i + 0], a0);
        a1 = fmaf(wr[i + 1], x[i + 1], a1);
        a2 = fmaf(wr[i + 2], x[i + 2], a2);
        a3 = fmaf(wr[i + 3], x[i + 3], a3);
      }
      a0 = fmaf(wr[64], x[64], a0);
      a1 = fmaf(wr[65], x[65], a1);
      a2 = fmaf(wr[66], x[66], a2);
      float acc = (a0 + a1) + (a2 + a3);
      XB[o * 65 + lane] = fmaxf(fmaf(acc, sc0[o], sh0[o]), 0.f);
    }
  }
  // ---- layer 1: 64 -> 64
  {
    float x[64];
#pragma unroll
    for (int i = 0; i < 64; i++) x[i] = XB[i * 65 + lane];
#pragma unroll 2
    for (int o = 0; o < 64; o++) {
      const float* wr = W1 + o * 64;
      float a0 = 0.f, a1 = 0.f, a2 = 0.f, a3 = 0.f;
#pragma unroll
      for (int i = 0; i < 64; i += 4) {
        a0 = fmaf(wr[i + 0], x[i + 0], a0);
        a1 = fmaf(wr[i + 1], x[i + 1], a1);
        a2 = fmaf(wr[i + 2], x[i + 2], a2);
        a3 = fmaf(wr[i + 3], x[i + 3], a3);
      }
      float acc = (a0 + a1) + (a2 + a3);
      XA[o * 65 + lane] = fmaxf(fmaf(acc, sc1[o], sh1[o]), 0.f);
    }
  }
  // ---- layer 2: 64 -> 128, fused max over samples (lanes)
  {
    float x[64];
#pragma unroll
    for (int i = 0; i < 64; i++) x[i] = XA[i * 65 + lane];
    float* ob = out_feat + (size_t)b * C2 * NPOINT + p;
#pragma unroll 2
    for (int o = 0; o < C2; o++) {
      const float* wr = W2 + o * 64;
      float a0 = 0.f, a1 = 0.f, a2 = 0.f, a3 = 0.f;
#pragma unroll
      for (int i = 0; i < 64; i += 4) {
        a0 = fmaf(wr[i + 0], x[i + 0], a0);
        a1 = fmaf(wr[i + 1], x[i + 1], a1);
        a2 = fmaf(wr[i + 2], x[i + 2], a2);
        a3 = fmaf(wr[i + 3], x[i + 3], a3);
      }
      float acc = (a0 + a1) + (a2 + a3);
      float y = fmaxf(fmaf(acc, sc2[o], sh2[o]), 0.f);
#pragma unroll
      for (int m = 1; m < 64; m <<= 1) y = fmaxf(y, __shfl_xor(y, m, 64));
      if (lane == 0) ob[(size_t)o * NPOINT] = y;
    }
  }
}

extern "C" void kernel_launch(void* const* d_in, const int* in_sizes, int n_in,
                              void* d_out, int out_size, void* d_ws, size_t ws_size,
                              hipStream_t stream) {
  const float* xyz  = (const float*)d_in[0];
  const float* feat = (const float*)d_in[1];
  const float* W0 = (const float*)d_in[2];
  const float* g0 = (const float*)d_in[3];
  const float* b0 = (const float*)d_in[4];
  const float* m0 = (const float*)d_in[5];
  const float* v0 = (const float*)d_in[6];
  const float* W1 = (const float*)d_in[7];
  const float* g1 = (const float*)d_in[8];
  const float* b1 = (const float*)d_in[9];
  const float* m1 = (const float*)d_in[10];
  const float* v1 = (const float*)d_in[11];
  const float* W2 = (const float*)d_in[12];
  const float* g2 = (const float*)d_in[13];
  const float* b2 = (const float*)d_in[14];
  const float* m2 = (const float*)d_in[15];
  const float* v2 = (const float*)d_in[16];

  float* out = (float*)d_out;
  float* out_xyz  = out;                         // (8,2048,3)   = 49152
  float* out_feat = out + 49152;                 // (8,128,2048) = 2097152
  float* out_inds = out + 49152 + 2097152;       // (8,2048)     = 16384

  int*   ball  = (int*)d_ws;                                            // 4 MiB
  float* featT = (float*)((char*)d_ws + (size_t)BATCH * NPOINT * NSAMPLE * 4);  // 16.8 MiB

  hipLaunchKernelGGL(fps_kernel, dim3(BATCH), dim3(512), 0, stream,
                     xyz, out_xyz, out_inds);
  hipLaunchKernelGGL(transpose_kernel, dim3(BATCH * (NPTS / 64)), dim3(256), 0, stream,
                     feat, featT);
  hipLaunchKernelGGL(ballq_kernel, dim3((BATCH * NPOINT) / 4), dim3(256), 0, stream,
                     xyz, out_xyz, ball);
  hipLaunchKernelGGL(mlp_kernel, dim3((BATCH * NPOINT) / 4), dim3(256), 0, stream,
                     xyz, featT, ball, out_xyz,
                     W0, g0, b0, m0, v0, W1, g1, b1, m1, v1,
                     W2, g2, b2, m2, v2, out_feat);
}

// Round 2
// 3306.867 us; speedup vs baseline: 1.7044x; 1.7044x over previous
//
#include <hip/hip_runtime.h>
#include <cstdint>
#include <cstddef>

#define BATCH   8
#define NPTS    8192
#define NPOINT  2048
#define NSAMPLE 64
#define K0      67      // 3 + 64 input channels
#define C2      128

// Exact-order squared distance, matching XLA/numpy: ((dx*dx + dy*dy) + dz*dz),
// separate mul/add (no FMA contraction), round-to-nearest f32.
__device__ __forceinline__ float d2e(float ax, float ay, float az,
                                     float bx, float by, float bz) {
#pragma clang fp contract(off)
  float dx = ax - bx;
  float dy = ay - by;
  float dz = az - bz;
  float t0 = dx * dx;
  float t1 = dy * dy;
  float t2 = dz * dz;
  return (t0 + t1) + t2;
}

__device__ __forceinline__ float2 comb2(float2 a, float2 b) {
  // (value desc, index asc) winner of two (v, idx-as-float-bits) pairs
  int ia = __float_as_int(a.y), ib = __float_as_int(b.y);
  bool take = (b.x > a.x) || (b.x == a.x && ib < ia);
  return take ? b : a;
}

// ---------------- FPS: one block per batch, serial 2047-step argmax ----------
// Thread tid owns contiguous points [tid*16, tid*16+16) so that argmax
// tie-break (first index) == (lowest j, lowest lane, lowest wave).
__global__ __launch_bounds__(512) void fps_kernel(const float* __restrict__ xyz,
                                                  float* __restrict__ out_xyz,
                                                  float* __restrict__ out_inds) {
  const int b = blockIdx.x;
  const int tid = threadIdx.x;
  const int lane = tid & 63, wid = tid >> 6;
  __shared__ float sx[NPTS], sy[NPTS], sz[NPTS];
  __shared__ float2 red[2][8];          // ping-pong: one barrier per iteration

  const float* xb = xyz + (size_t)b * NPTS * 3;
  // coalesced stage to LDS
  for (int j = 0; j < 16; j++) {
    int i = tid + 512 * j;
    sx[i] = xb[i * 3 + 0];
    sy[i] = xb[i * 3 + 1];
    sz[i] = xb[i * 3 + 2];
  }
  __syncthreads();

  const float x0 = sx[0], y0 = sy[0], z0 = sz[0];
  const int base = tid * 16;
  float px[16], py[16], pz[16], dd[16];
#pragma unroll
  for (int j = 0; j < 16; j++) {
    px[j] = sx[base + j]; py[j] = sy[base + j]; pz[j] = sz[base + j];
    dd[j] = d2e(px[j], py[j], pz[j], x0, y0, z0);
  }
  if (tid == 0) {
    out_inds[b * NPOINT] = 0.f;
    out_xyz[(size_t)b * NPOINT * 3 + 0] = x0;
    out_xyz[(size_t)b * NPOINT * 3 + 1] = y0;
    out_xyz[(size_t)b * NPOINT * 3 + 2] = z0;
  }

  for (int t = 1; t < NPOINT; ++t) {
    // per-thread argmax over its 16 (strict > : first j wins)
    float bv = dd[0]; int bj = 0;
#pragma unroll
    for (int j = 1; j < 16; j++) {
      if (dd[j] > bv) { bv = dd[j]; bj = j; }
    }
    // wave value-only max; lowest winning lane = lowest index (ownership is
    // contiguous ascending in lane)
    float v = bv;
#pragma unroll
    for (int m = 1; m < 64; m <<= 1) v = fmaxf(v, __shfl_xor(v, m, 64));
    unsigned long long msk = __ballot(v == bv);
    int src = __ffsll(msk) - 1;
    int widx = __shfl(base + bj, src, 64);

    const int par = t & 1;
    if (lane == 0) red[par][wid] = make_float2(v, __int_as_float(widx));
    __syncthreads();   // the only barrier per iteration

    float2 c0 = red[par][0], c1 = red[par][1], c2 = red[par][2], c3 = red[par][3];
    float2 c4 = red[par][4], c5 = red[par][5], c6 = red[par][6], c7 = red[par][7];
    c0 = comb2(c0, c1); c2 = comb2(c2, c3); c4 = comb2(c4, c5); c6 = comb2(c6, c7);
    c0 = comb2(c0, c2); c4 = comb2(c4, c6);
    c0 = comb2(c0, c4);
    const int nxt = __float_as_int(c0.y);

    const float qx = sx[nxt], qy = sy[nxt], qz = sz[nxt];
    if (tid == 0) {
      out_inds[b * NPOINT + t] = (float)nxt;
      out_xyz[((size_t)b * NPOINT + t) * 3 + 0] = qx;
      out_xyz[((size_t)b * NPOINT + t) * 3 + 1] = qy;
      out_xyz[((size_t)b * NPOINT + t) * 3 + 2] = qz;
    }
#pragma unroll
    for (int j = 0; j < 16; j++)
      dd[j] = fminf(dd[j], d2e(px[j], py[j], pz[j], qx, qy, qz));
  }
}

// ---------------- feature transpose: [b][c][n] -> [b][n][c] ------------------
__global__ __launch_bounds__(256) void transpose_kernel(const float* __restrict__ feat,
                                                        float* __restrict__ featT) {
  __shared__ float tile[64][65];
  const int bt = blockIdx.x;          // b*128 + ntile
  const int b = bt >> 7, nt = bt & 127;
  const int tid = threadIdx.x;
  const int r0 = tid >> 6, cc = tid & 63;
  const float* fb = feat + (size_t)b * 64 * NPTS + (size_t)nt * 64;
#pragma unroll
  for (int r = r0; r < 64; r += 4)
    tile[r][cc] = fb[(size_t)r * NPTS + cc];
  __syncthreads();
  float* ob = featT + ((size_t)b * NPTS + (size_t)nt * 64) * 64;
#pragma unroll
  for (int n = r0; n < 64; n += 4)
    ob[(size_t)n * 64 + cc] = tile[cc][n];
}

// ---------------- ball query: one wave per query point -----------------------
__global__ __launch_bounds__(256) void ballq_kernel(const float* __restrict__ xyz,
                                                    const float* __restrict__ new_xyz,
                                                    int* __restrict__ ball) {
  const int lane = threadIdx.x & 63;
  const int q = blockIdx.x * 4 + (threadIdx.x >> 6);
  const int b = q >> 11;
  const float RR = (float)(0.4 * 0.4);
  const float cx = new_xyz[(size_t)q * 3 + 0];
  const float cy = new_xyz[(size_t)q * 3 + 1];
  const float cz = new_xyz[(size_t)q * 3 + 2];
  const float* xb = xyz + (size_t)b * NPTS * 3;
  int cnt = 0, firsti = -1;
  for (int base = 0; base < NPTS; base += 64) {
    int i = base + lane;
    float xx = xb[i * 3 + 0], yy = xb[i * 3 + 1], zz = xb[i * 3 + 2];
    float d2 = d2e(xx, yy, zz, cx, cy, cz);
    bool m = d2 < RR;
    unsigned long long mask = __ballot(m);
    if (mask) {
      if (firsti < 0) firsti = base + (__ffsll((unsigned long long)mask) - 1);
      int pos = cnt + (int)__popcll(mask & ((1ull << lane) - 1ull));
      if (m && pos < NSAMPLE) ball[(size_t)q * NSAMPLE + pos] = i;
      cnt += (int)__popcll(mask);
      if (cnt >= NSAMPLE) break;
    }
  }
  // pad with first in-radius index (center itself is always in-radius -> cnt>=1)
  for (int s = cnt + lane; s < NSAMPLE; s += 64)
    ball[(size_t)q * NSAMPLE + s] = firsti;
}

// ---------------- grouped MLP (3 layers) + max-pool: one wave per point ------
// lane == sample. Each lane gathers its own feature row (the exact x-vector it
// consumes), keeps x/y0/y1 in registers; no activation LDS at all.
__global__ __launch_bounds__(256) void mlp_kernel(
    const float* __restrict__ xyz, const float* __restrict__ featT,
    const int* __restrict__ ball, const float* __restrict__ new_xyz,
    const float* __restrict__ W0, const float* __restrict__ g0,
    const float* __restrict__ b0, const float* __restrict__ m0,
    const float* __restrict__ v0, const float* __restrict__ W1,
    const float* __restrict__ g1, const float* __restrict__ b1,
    const float* __restrict__ m1, const float* __restrict__ v1,
    const float* __restrict__ W2, const float* __restrict__ g2,
    const float* __restrict__ b2, const float* __restrict__ m2,
    const float* __restrict__ v2, float* __restrict__ out_feat) {
  __shared__ float sc0[64], sh0[64], sc1[64], sh1[64], sc2[128], sh2[128];
  const int tid = threadIdx.x;
  const int lane = tid & 63, wid = tid >> 6;

  if (tid < 64) {
    float s = g0[tid] / sqrtf(v0[tid] + 1e-5f);
    sc0[tid] = s; sh0[tid] = b0[tid] - m0[tid] * s;
  } else if (tid < 128) {
    int t = tid - 64;
    float s = g1[t] / sqrtf(v1[t] + 1e-5f);
    sc1[t] = s; sh1[t] = b1[t] - m1[t] * s;
  } else {
    int t = tid - 128;
    float s = g2[t] / sqrtf(v2[t] + 1e-5f);
    sc2[t] = s; sh2[t] = b2[t] - m2[t] * s;
  }
  __syncthreads();

  const int q = blockIdx.x * 4 + wid;
  const int b = q >> 11, p = q & 2047;

  const float cx = new_xyz[(size_t)q * 3 + 0];
  const float cy = new_xyz[(size_t)q * 3 + 1];
  const float cz = new_xyz[(size_t)q * 3 + 2];
  const int sidx = ball[(size_t)q * NSAMPLE + lane];
  const float* xb = xyz + (size_t)b * NPTS * 3;

  float x[K0];
  x[0] = xb[(size_t)sidx * 3 + 0] - cx;
  x[1] = xb[(size_t)sidx * 3 + 1] - cy;
  x[2] = xb[(size_t)sidx * 3 + 2] - cz;
  const float4* row =
      (const float4*)(featT + ((size_t)b * NPTS + (size_t)sidx) * 64);
#pragma unroll
  for (int i = 0; i < 16; i++) {
    float4 v = row[i];
    x[3 + 4 * i + 0] = v.x; x[3 + 4 * i + 1] = v.y;
    x[3 + 4 * i + 2] = v.z; x[3 + 4 * i + 3] = v.w;
  }

  // ---- layer 0: 67 -> 64 (full unroll: y0 statically indexed)
  float y0r[64];
#pragma unroll
  for (int o = 0; o < 64; o++) {
    const float* wr = W0 + o * K0;
    float a0 = 0.f, a1 = 0.f, a2 = 0.f, a3 = 0.f;
#pragma unroll
    for (int i = 0; i < 64; i += 4) {
      a0 = fmaf(wr[i + 0], x[i + 0], a0);
      a1 = fmaf(wr[i + 1], x[i + 1], a1);
      a2 = fmaf(wr[i + 2], x[i + 2], a2);
      a3 = fmaf(wr[i + 3], x[i + 3], a3);
    }
    a0 = fmaf(wr[64], x[64], a0);
    a1 = fmaf(wr[65], x[65], a1);
    a2 = fmaf(wr[66], x[66], a2);
    float acc = (a0 + a1) + (a2 + a3);
    y0r[o] = fmaxf(fmaf(acc, sc0[o], sh0[o]), 0.f);
  }
  // ---- layer 1: 64 -> 64
  float y1r[64];
#pragma unroll
  for (int o = 0; o < 64; o++) {
    const float* wr = W1 + o * 64;
    float a0 = 0.f, a1 = 0.f, a2 = 0.f, a3 = 0.f;
#pragma unroll
    for (int i = 0; i < 64; i += 4) {
      a0 = fmaf(wr[i + 0], y0r[i + 0], a0);
      a1 = fmaf(wr[i + 1], y0r[i + 1], a1);
      a2 = fmaf(wr[i + 2], y0r[i + 2], a2);
      a3 = fmaf(wr[i + 3], y0r[i + 3], a3);
    }
    float acc = (a0 + a1) + (a2 + a3);
    y1r[o] = fmaxf(fmaf(acc, sc1[o], sh1[o]), 0.f);
  }
  // ---- layer 2: 64 -> 128, fused max over samples (lanes); o dynamic is fine
  float* ob = out_feat + (size_t)b * C2 * NPOINT + p;
#pragma unroll 2
  for (int o = 0; o < C2; o++) {
    const float* wr = W2 + o * 64;
    float a0 = 0.f, a1 = 0.f, a2 = 0.f, a3 = 0.f;
#pragma unroll
    for (int i = 0; i < 64; i += 4) {
      a0 = fmaf(wr[i + 0], y1r[i + 0], a0);
      a1 = fmaf(wr[i + 1], y1r[i + 1], a1);
      a2 = fmaf(wr[i + 2], y1r[i + 2], a2);
      a3 = fmaf(wr[i + 3], y1r[i + 3], a3);
    }
    float acc = (a0 + a1) + (a2 + a3);
    float y = fmaxf(fmaf(acc, sc2[o], sh2[o]), 0.f);
#pragma unroll
    for (int m = 1; m < 64; m <<= 1) y = fmaxf(y, __shfl_xor(y, m, 64));
    if (lane == 0) ob[(size_t)o * NPOINT] = y;
  }
}

extern "C" void kernel_launch(void* const* d_in, const int* in_sizes, int n_in,
                              void* d_out, int out_size, void* d_ws, size_t ws_size,
                              hipStream_t stream) {
  const float* xyz  = (const float*)d_in[0];
  const float* feat = (const float*)d_in[1];
  const float* W0 = (const float*)d_in[2];
  const float* g0 = (const float*)d_in[3];
  const float* b0 = (const float*)d_in[4];
  const float* m0 = (const float*)d_in[5];
  const float* v0 = (const float*)d_in[6];
  const float* W1 = (const float*)d_in[7];
  const float* g1 = (const float*)d_in[8];
  const float* b1 = (const float*)d_in[9];
  const float* m1 = (const float*)d_in[10];
  const float* v1 = (const float*)d_in[11];
  const float* W2 = (const float*)d_in[12];
  const float* g2 = (const float*)d_in[13];
  const float* b2 = (const float*)d_in[14];
  const float* m2 = (const float*)d_in[15];
  const float* v2 = (const float*)d_in[16];

  float* out = (float*)d_out;
  float* out_xyz  = out;                         // (8,2048,3)   = 49152
  float* out_feat = out + 49152;                 // (8,128,2048) = 2097152
  float* out_inds = out + 49152 + 2097152;       // (8,2048)     = 16384

  int*   ball  = (int*)d_ws;                                            // 4 MiB
  float* featT = (float*)((char*)d_ws + (size_t)BATCH * NPOINT * NSAMPLE * 4);  // 16.8 MiB

  hipLaunchKernelGGL(fps_kernel, dim3(BATCH), dim3(512), 0, stream,
                     xyz, out_xyz, out_inds);
  hipLaunchKernelGGL(transpose_kernel, dim3(BATCH * (NPTS / 64)), dim3(256), 0, stream,
                     feat, featT);
  hipLaunchKernelGGL(ballq_kernel, dim3((BATCH * NPOINT) / 4), dim3(256), 0, stream,
                     xyz, out_xyz, ball);
  hipLaunchKernelGGL(mlp_kernel, dim3((BATCH * NPOINT) / 4), dim3(256), 0, stream,
                     xyz, featT, ball, out_xyz,
                     W0, g0, b0, m0, v0, W1, g1, b1, m1, v1,
                     W2, g2, b2, m2, v2, out_feat);
}